// Round 1
// baseline (578.763 us; speedup 1.0000x reference)
//
#include <hip/hip_runtime.h>
#include <hip/hip_bf16.h>

// Problem constants
#define NTOK 4096          // N
#define BNROWS 8192        // B*N
#define EDIM 128
#define FDIM 512

#define EP_NONE 0
#define EP_RESID 1
#define EP_RELU_BIAS 2
#define EP_BIAS_RESID 3

// ---------------------------------------------------------------------------
// RMSNorm: one wave (64 lanes) per row of 128; block = (64,4) -> 4 rows/block
// ---------------------------------------------------------------------------
__global__ void rmsnorm_k(const float* __restrict__ x, const float* __restrict__ w,
                          float* __restrict__ y) {
    int row  = blockIdx.x * 4 + threadIdx.y;
    int lane = threadIdx.x;
    const float2* xr = (const float2*)(x + (size_t)row * EDIM);
    float2 v = xr[lane];
    float ss = v.x * v.x + v.y * v.y;
#pragma unroll
    for (int off = 32; off > 0; off >>= 1) ss += __shfl_down(ss, off, 64);
    ss = __shfl(ss, 0, 64);
    float r = rsqrtf(ss * (1.0f / 128.0f) + 1e-6f);
    float2 wv = ((const float2*)w)[lane];
    float2 o; o.x = v.x * r * wv.x; o.y = v.y * r * wv.y;
    ((float2*)(y + (size_t)row * EDIM))[lane] = o;
}

// ---------------------------------------------------------------------------
// Generic fp32 GEMM body: y[r,c] (+epilogue) = sum_k x[r,k] * W[c,k]
// 128x128 tile, 256 threads, 8x8 micro-tile, KC=64.
// LDS tiles stored k-major (transposed on staging) -> float4 reads, no pad
// needed (all accesses <=2-way bank aliased, which is free on CDNA4).
// ---------------------------------------------------------------------------
template<int EPIL>
__device__ __forceinline__ void gemm_body(
    const float* __restrict__ x, const float* __restrict__ Wm,
    const float* __restrict__ bias, const float* __restrict__ resid,
    float* __restrict__ y, int Ctot, int kstride,
    int r0, int c0, int k0, int k1)
{
    __shared__ float xt[64][128];   // [k][r]
    __shared__ float wt[64][128];   // [k][c]
    const int t  = threadIdx.x;
    const int tx = t & 15;          // col group
    const int ty = t >> 4;          // row group
    float acc[8][8] = {};

    const int rr   = t >> 1;        // 0..127 (row / weight-row being staged)
    const int koff = (t & 1) * 32;

    for (int kc = k0; kc < k1; kc += 64) {
        const float4* xs = (const float4*)(x  + (size_t)(r0 + rr) * kstride + kc + koff);
        const float4* wsrc = (const float4*)(Wm + (size_t)(c0 + rr) * kstride + kc + koff);
#pragma unroll
        for (int u = 0; u < 8; ++u) {
            float4 f = xs[u];
            int kk = koff + 4 * u;
            xt[kk + 0][rr] = f.x; xt[kk + 1][rr] = f.y;
            xt[kk + 2][rr] = f.z; xt[kk + 3][rr] = f.w;
        }
#pragma unroll
        for (int u = 0; u < 8; ++u) {
            float4 f = wsrc[u];
            int kk = koff + 4 * u;
            wt[kk + 0][rr] = f.x; wt[kk + 1][rr] = f.y;
            wt[kk + 2][rr] = f.z; wt[kk + 3][rr] = f.w;
        }
        __syncthreads();
#pragma unroll 4
        for (int k = 0; k < 64; ++k) {
            float4 a0 = *(const float4*)&xt[k][4 * ty];
            float4 a1 = *(const float4*)&xt[k][64 + 4 * ty];
            float4 b0 = *(const float4*)&wt[k][4 * tx];
            float4 b1 = *(const float4*)&wt[k][64 + 4 * tx];
            float av[8] = {a0.x, a0.y, a0.z, a0.w, a1.x, a1.y, a1.z, a1.w};
            float bv[8] = {b0.x, b0.y, b0.z, b0.w, b1.x, b1.y, b1.z, b1.w};
#pragma unroll
            for (int i = 0; i < 8; ++i)
#pragma unroll
                for (int j = 0; j < 8; ++j)
                    acc[i][j] = fmaf(av[i], bv[j], acc[i][j]);
        }
        __syncthreads();
    }

#pragma unroll
    for (int i = 0; i < 8; ++i) {
        int row = r0 + ((i < 4) ? (4 * ty + i) : (64 + 4 * ty + (i - 4)));
#pragma unroll
        for (int jh = 0; jh < 2; ++jh) {
            int col = c0 + ((jh == 0) ? (4 * tx) : (64 + 4 * tx));
            float4 st;
            st.x = acc[i][4 * jh + 0]; st.y = acc[i][4 * jh + 1];
            st.z = acc[i][4 * jh + 2]; st.w = acc[i][4 * jh + 3];
            size_t off = (size_t)row * Ctot + col;
            if (EPIL == EP_RELU_BIAS || EPIL == EP_BIAS_RESID) {
                float4 bb = *(const float4*)&bias[col];
                st.x += bb.x; st.y += bb.y; st.z += bb.z; st.w += bb.w;
            }
            if (EPIL == EP_RESID || EPIL == EP_BIAS_RESID) {
                float4 rv = *(const float4*)&resid[off];
                st.x += rv.x; st.y += rv.y; st.z += rv.z; st.w += rv.w;
            }
            if (EPIL == EP_RELU_BIAS) {
                st.x = fmaxf(st.x, 0.f); st.y = fmaxf(st.y, 0.f);
                st.z = fmaxf(st.z, 0.f); st.w = fmaxf(st.w, 0.f);
            }
            *(float4*)&y[off] = st;
        }
    }
}

template<int EPIL>
__launch_bounds__(256, 2)
__global__ void gemm_wt_k(const float* __restrict__ x, const float* __restrict__ Wm,
                          const float* __restrict__ bias, const float* __restrict__ resid,
                          float* __restrict__ y, int Ctot, int kstride) {
    gemm_body<EPIL>(x, Wm, bias, resid, y, Ctot, kstride,
                    blockIdx.x * 128, blockIdx.y * 128, 0, kstride);
}

// Fused q/k/v projection: blockIdx.y selects which weight/output (3-way).
__launch_bounds__(256, 2)
__global__ void gemm_qkv_k(const float* __restrict__ h,
                           const float* __restrict__ Wq, const float* __restrict__ Wk2,
                           const float* __restrict__ Wv2,
                           float* __restrict__ q, float* __restrict__ kk, float* __restrict__ vv) {
    const float* Wm = (blockIdx.y == 0) ? Wq : ((blockIdx.y == 1) ? Wk2 : Wv2);
    float* y        = (blockIdx.y == 0) ? q  : ((blockIdx.y == 1) ? kk  : vv);
    gemm_body<EP_NONE>(h, Wm, nullptr, nullptr, y, 128, 128, blockIdx.x * 128, 0, 0, 128);
}

// FFN2 K-split partials (K=512 split 4 ways -> 256 blocks)
__launch_bounds__(256, 2)
__global__ void ffn2_part_k(const float* __restrict__ mid, const float* __restrict__ W2,
                            float* __restrict__ p0, float* __restrict__ p1,
                            float* __restrict__ p2, float* __restrict__ p3) {
    int ks = blockIdx.z;
    float* y = (ks == 0) ? p0 : (ks == 1) ? p1 : (ks == 2) ? p2 : p3;
    gemm_body<EP_NONE>(mid, W2, nullptr, nullptr, y, 128, 512,
                       blockIdx.x * 128, 0, ks * 128, ks * 128 + 128);
}

// ---------------------------------------------------------------------------
// qkv transform: sigq = sigmoid(q) (in place over q); M = [exp(k)*v | exp(k)]
// ---------------------------------------------------------------------------
__global__ void qkv_transform_k(float* __restrict__ q, const float* __restrict__ k,
                                const float* __restrict__ v, float* __restrict__ M) {
    int idx = blockIdx.x * 256 + threadIdx.x;
    int r = idx >> 7, e = idx & 127;
    float kw = __expf(k[idx]);
    float vv = v[idx];
    float qq = q[idx];
    q[idx] = 1.0f / (1.0f + __expf(-qq));
    M[((size_t)r << 8) + e]       = kw * vv;
    M[((size_t)r << 8) + 128 + e] = kw;
}

// ---------------------------------------------------------------------------
// Big GEMM: out[j,c] = sum_i exp(coef*dis[b,j,i]) * M[b,i,c]   (dis symmetric)
// 128x128 tile, 8x8 micro, KC=32, K-split 2 (z = b + 2*ks).
// ks=0 writes wb0 (both batches contiguous); ks=1 writes s0 (b=0) / s1 (b=1).
// ---------------------------------------------------------------------------
__launch_bounds__(256, 2)
__global__ void big_gemm_k(const float* __restrict__ dis, const float* __restrict__ alphap,
                           const float* __restrict__ M,
                           float* __restrict__ wb0, float* __restrict__ s0,
                           float* __restrict__ s1) {
    __shared__ float at[32][132];   // [k][j], exp applied
    __shared__ float bt[32][132];   // [k][c]
    const int t  = threadIdx.x;
    const int tx = t & 15;
    const int ty = t >> 4;
    const int j0 = blockIdx.x * 128;
    const int c0 = blockIdx.y * 128;
    const int b  = blockIdx.z & 1;
    const int ksp = blockIdx.z >> 1;
    const float coef = -alphap[0] * 12.0f;   // log2(4096) = 12
    const float* disb = dis + (size_t)b * NTOK * NTOK;
    const float* Mb   = M   + (size_t)b * NTOK * 256;
    float* obase = (ksp == 0) ? (wb0 + (size_t)b * NTOK * 256) : ((b == 0) ? s0 : s1);

    float acc[8][8] = {};
    const int rr    = t >> 1;          // 0..127 j-row staged
    const int koffA = (t & 1) * 16;
    const int kb    = t >> 3;          // 0..31 k-row of B staged
    const int coffB = (t & 7) * 16;
    const int k0 = ksp * (NTOK / 2), k1 = k0 + (NTOK / 2);

    for (int kc = k0; kc < k1; kc += 32) {
        const float4* as = (const float4*)(disb + (size_t)(j0 + rr) * NTOK + kc + koffA);
#pragma unroll
        for (int u = 0; u < 4; ++u) {
            float4 f = as[u];
            int kk2 = koffA + 4 * u;
            at[kk2 + 0][rr] = __expf(coef * f.x);
            at[kk2 + 1][rr] = __expf(coef * f.y);
            at[kk2 + 2][rr] = __expf(coef * f.z);
            at[kk2 + 3][rr] = __expf(coef * f.w);
        }
        const float4* bs = (const float4*)(Mb + (size_t)(kc + kb) * 256 + c0 + coffB);
        float4* bd = (float4*)&bt[kb][coffB];
#pragma unroll
        for (int u = 0; u < 4; ++u) bd[u] = bs[u];
        __syncthreads();
#pragma unroll 4
        for (int k = 0; k < 32; ++k) {
            float4 a0 = *(const float4*)&at[k][4 * ty];
            float4 a1 = *(const float4*)&at[k][64 + 4 * ty];
            float4 b0 = *(const float4*)&bt[k][4 * tx];
            float4 b1 = *(const float4*)&bt[k][64 + 4 * tx];
            float av[8] = {a0.x, a0.y, a0.z, a0.w, a1.x, a1.y, a1.z, a1.w};
            float bv[8] = {b0.x, b0.y, b0.z, b0.w, b1.x, b1.y, b1.z, b1.w};
#pragma unroll
            for (int i = 0; i < 8; ++i)
#pragma unroll
                for (int j = 0; j < 8; ++j)
                    acc[i][j] = fmaf(av[i], bv[j], acc[i][j]);
        }
        __syncthreads();
    }

#pragma unroll
    for (int i = 0; i < 8; ++i) {
        int j = j0 + ((i < 4) ? (4 * ty + i) : (64 + 4 * ty + (i - 4)));
#pragma unroll
        for (int jh = 0; jh < 2; ++jh) {
            int c = c0 + ((jh == 0) ? (4 * tx) : (64 + 4 * tx));
            float4 st;
            st.x = acc[i][4 * jh + 0]; st.y = acc[i][4 * jh + 1];
            st.z = acc[i][4 * jh + 2]; st.w = acc[i][4 * jh + 3];
            *(float4*)&obase[(size_t)j * 256 + c] = st;
        }
    }
}

// ---------------------------------------------------------------------------
// attn epilogue: attn = sigmoid(q) * (w1/w2), summing the two K-split halves
// ---------------------------------------------------------------------------
__global__ void attn_ep_k(const float* __restrict__ sigq, const float* __restrict__ wb0,
                          const float* __restrict__ s0, const float* __restrict__ s1,
                          float* __restrict__ attn) {
    int idx = blockIdx.x * 256 + threadIdx.x;
    int r = idx >> 7, e = idx & 127;
    size_t base = ((size_t)r << 8);
    const float* sp = (r < NTOK) ? s0 : s1;
    size_t sbase = ((size_t)(r & (NTOK - 1)) << 8);
    float w1 = wb0[base + e]       + sp[sbase + e];
    float w2 = wb0[base + 128 + e] + sp[sbase + 128 + e];
    attn[idx] = sigq[idx] * (w1 / w2);
}

// final: out = out1 + b2 + p0 + p1 + p2 + p3(=d_out in place)
__global__ void final_add_k(const float* __restrict__ out1, const float* __restrict__ b2,
                            const float* __restrict__ p0, const float* __restrict__ p1,
                            const float* __restrict__ p2, float* __restrict__ outp) {
    int idx = blockIdx.x * 256 + threadIdx.x;
    int e = idx & 127;
    outp[idx] = out1[idx] + b2[e] + p0[idx] + p1[idx] + p2[idx] + outp[idx];
}

// ---------------------------------------------------------------------------
extern "C" void kernel_launch(void* const* d_in, const int* in_sizes, int n_in,
                              void* d_out, int out_size, void* d_ws, size_t ws_size,
                              hipStream_t stream) {
    const float* input1 = (const float*)d_in[0];
    const float* dis    = (const float*)d_in[1];
    const float* Wq     = (const float*)d_in[2];
    const float* Wk     = (const float*)d_in[3];
    const float* Wv     = (const float*)d_in[4];
    const float* alpha  = (const float*)d_in[5];
    const float* ln1    = (const float*)d_in[6];
    const float* ln2    = (const float*)d_in[7];
    const float* Wcomb  = (const float*)d_in[8];
    const float* W1     = (const float*)d_in[9];
    const float* b1     = (const float*)d_in[10];
    const float* W2     = (const float*)d_in[11];
    const float* b2     = (const float*)d_in[12];
    float* out = (float*)d_out;

    // workspace overlay (8M floats = 32 MiB total)
    const size_t MEG = 1u << 20;    // = BNROWS*128
    float* ws = (float*)d_ws;
    float* bH = ws;                 // h -> Wsplit(b0) -> h2 -> ffn2 partial0
    float* bQ = ws + 1 * MEG;       // q/sigq -> ffn2 partial1
    float* bK = ws + 2 * MEG;       // k -> Wsplit(b1) -> out1 (live to end)
    float* bV = ws + 3 * MEG;       // v -> attn -> ffn2 partial2
    float* bM = ws + 4 * MEG;       // M [BN][256] (2M floats)
    float* bW = ws + 6 * MEG;       // Wb0 [BN][256] (2M floats)
    float* mid = bM;                // ffn mid [BN][512] (4M floats, reuses M+Wb0)

    // 1) h = rmsnorm(input1, ln1)
    rmsnorm_k<<<dim3(BNROWS / 4), dim3(64, 4), 0, stream>>>(input1, ln1, bH);
    // 2) q,k,v projections (fused 3-way)
    gemm_qkv_k<<<dim3(64, 3), 256, 0, stream>>>(bH, Wq, Wk, Wv, bQ, bK, bV);
    // 3) sigq (in place), M = [exp(k)*v | exp(k)]
    qkv_transform_k<<<dim3(4096), 256, 0, stream>>>(bQ, bK, bV, bM);
    // 4) big GEMM with fused exp(-12*dis), K-split 2
    big_gemm_k<<<dim3(32, 2, 4), 256, 0, stream>>>(dis, alpha, bM, bW, bH, bK);
    // 5) attn = sigq * w1/w2  (sum split halves)
    attn_ep_k<<<dim3(4096), 256, 0, stream>>>(bQ, bW, bH, bK, bV);
    // 6) out1 = input1 + attn @ Wcomb.T
    gemm_wt_k<EP_RESID><<<dim3(64, 1), 256, 0, stream>>>(bV, Wcomb, nullptr, input1, bK, 128, 128);
    // 7) h2 = rmsnorm(out1, ln2)
    rmsnorm_k<<<dim3(BNROWS / 4), dim3(64, 4), 0, stream>>>(bK, ln2, bH);
    // 8) mid = relu(h2 @ W1.T + b1)
    gemm_wt_k<EP_RELU_BIAS><<<dim3(64, 4), 256, 0, stream>>>(bH, W1, b1, nullptr, mid, 512, 128);
    // 9) ffn2 partials (K-split 4)
    ffn2_part_k<<<dim3(64, 1, 4), 256, 0, stream>>>(mid, W2, bH, bQ, bV, out);
    // 10) out = out1 + b2 + sum(partials)
    final_add_k<<<dim3(4096), 256, 0, stream>>>(bK, b2, bH, bQ, bV, out);
}

// Round 4
// 371.171 us; speedup vs baseline: 1.5593x; 1.5593x over previous
//
#include <hip/hip_runtime.h>
#include <hip/hip_bf16.h>

// Problem constants
#define NTOK 4096          // N
#define BNROWS 8192        // B*N
#define EDIM 128
#define FDIM 512

#define EP_NONE 0
#define EP_RESID 1
#define EP_RELU_BIAS 2
#define EP_BIAS_RESID 3

typedef __attribute__((ext_vector_type(8))) short bf16x8;
typedef __attribute__((ext_vector_type(4))) float f32x4;

__device__ __forceinline__ ushort f2bf(float x) {
    union { float f; unsigned u; } c; c.f = x;
    unsigned r = c.u + 0x7FFF + ((c.u >> 16) & 1);
    return (ushort)(r >> 16);
}

// ---------------------------------------------------------------------------
// RMSNorm: one wave (64 lanes) per row of 128; block = (64,4) -> 4 rows/block
// ---------------------------------------------------------------------------
__global__ void rmsnorm_k(const float* __restrict__ x, const float* __restrict__ w,
                          float* __restrict__ y) {
    int row  = blockIdx.x * 4 + threadIdx.y;
    int lane = threadIdx.x;
    const float2* xr = (const float2*)(x + (size_t)row * EDIM);
    float2 v = xr[lane];
    float ss = v.x * v.x + v.y * v.y;
#pragma unroll
    for (int off = 32; off > 0; off >>= 1) ss += __shfl_down(ss, off, 64);
    ss = __shfl(ss, 0, 64);
    float r = rsqrtf(ss * (1.0f / 128.0f) + 1e-6f);
    float2 wv = ((const float2*)w)[lane];
    float2 o; o.x = v.x * r * wv.x; o.y = v.y * r * wv.y;
    ((float2*)(y + (size_t)row * EDIM))[lane] = o;
}

// ---------------------------------------------------------------------------
// Generic fp32 GEMM body (small GEMMs): y[r,c] = sum_k x[r,k] * W[c,k]
// ---------------------------------------------------------------------------
template<int EPIL>
__device__ __forceinline__ void gemm_body(
    const float* __restrict__ x, const float* __restrict__ Wm,
    const float* __restrict__ bias, const float* __restrict__ resid,
    float* __restrict__ y, int Ctot, int kstride,
    int r0, int c0, int k0, int k1)
{
    __shared__ float xt[64][128];   // [k][r]
    __shared__ float wt[64][128];   // [k][c]
    const int t  = threadIdx.x;
    const int tx = t & 15;          // col group
    const int ty = t >> 4;          // row group
    float acc[8][8] = {};

    const int rr   = t >> 1;        // 0..127
    const int koff = (t & 1) * 32;

    for (int kc = k0; kc < k1; kc += 64) {
        const float4* xs = (const float4*)(x  + (size_t)(r0 + rr) * kstride + kc + koff);
        const float4* wsrc = (const float4*)(Wm + (size_t)(c0 + rr) * kstride + kc + koff);
#pragma unroll
        for (int u = 0; u < 8; ++u) {
            float4 f = xs[u];
            int kk = koff + 4 * u;
            xt[kk + 0][rr] = f.x; xt[kk + 1][rr] = f.y;
            xt[kk + 2][rr] = f.z; xt[kk + 3][rr] = f.w;
        }
#pragma unroll
        for (int u = 0; u < 8; ++u) {
            float4 f = wsrc[u];
            int kk = koff + 4 * u;
            wt[kk + 0][rr] = f.x; wt[kk + 1][rr] = f.y;
            wt[kk + 2][rr] = f.z; wt[kk + 3][rr] = f.w;
        }
        __syncthreads();
#pragma unroll 4
        for (int k = 0; k < 64; ++k) {
            float4 a0 = *(const float4*)&xt[k][4 * ty];
            float4 a1 = *(const float4*)&xt[k][64 + 4 * ty];
            float4 b0 = *(const float4*)&wt[k][4 * tx];
            float4 b1 = *(const float4*)&wt[k][64 + 4 * tx];
            float av[8] = {a0.x, a0.y, a0.z, a0.w, a1.x, a1.y, a1.z, a1.w};
            float bv[8] = {b0.x, b0.y, b0.z, b0.w, b1.x, b1.y, b1.z, b1.w};
#pragma unroll
            for (int i = 0; i < 8; ++i)
#pragma unroll
                for (int j = 0; j < 8; ++j)
                    acc[i][j] = fmaf(av[i], bv[j], acc[i][j]);
        }
        __syncthreads();
    }

#pragma unroll
    for (int i = 0; i < 8; ++i) {
        int row = r0 + ((i < 4) ? (4 * ty + i) : (64 + 4 * ty + (i - 4)));
#pragma unroll
        for (int jh = 0; jh < 2; ++jh) {
            int col = c0 + ((jh == 0) ? (4 * tx) : (64 + 4 * tx));
            float4 st;
            st.x = acc[i][4 * jh + 0]; st.y = acc[i][4 * jh + 1];
            st.z = acc[i][4 * jh + 2]; st.w = acc[i][4 * jh + 3];
            size_t off = (size_t)row * Ctot + col;
            if (EPIL == EP_RELU_BIAS || EPIL == EP_BIAS_RESID) {
                float4 bb = *(const float4*)&bias[col];
                st.x += bb.x; st.y += bb.y; st.z += bb.z; st.w += bb.w;
            }
            if (EPIL == EP_RESID || EPIL == EP_BIAS_RESID) {
                float4 rv = *(const float4*)&resid[off];
                st.x += rv.x; st.y += rv.y; st.z += rv.z; st.w += rv.w;
            }
            if (EPIL == EP_RELU_BIAS) {
                st.x = fmaxf(st.x, 0.f); st.y = fmaxf(st.y, 0.f);
                st.z = fmaxf(st.z, 0.f); st.w = fmaxf(st.w, 0.f);
            }
            *(float4*)&y[off] = st;
        }
    }
}

template<int EPIL>
__launch_bounds__(256, 2)
__global__ void gemm_wt_k(const float* __restrict__ x, const float* __restrict__ Wm,
                          const float* __restrict__ bias, const float* __restrict__ resid,
                          float* __restrict__ y, int Ctot, int kstride) {
    gemm_body<EPIL>(x, Wm, bias, resid, y, Ctot, kstride,
                    blockIdx.x * 128, blockIdx.y * 128, 0, kstride);
}

__launch_bounds__(256, 2)
__global__ void gemm_qkv_k(const float* __restrict__ h,
                           const float* __restrict__ Wq, const float* __restrict__ Wk2,
                           const float* __restrict__ Wv2,
                           float* __restrict__ q, float* __restrict__ kk, float* __restrict__ vv) {
    const float* Wm = (blockIdx.y == 0) ? Wq : ((blockIdx.y == 1) ? Wk2 : Wv2);
    float* y        = (blockIdx.y == 0) ? q  : ((blockIdx.y == 1) ? kk  : vv);
    gemm_body<EP_NONE>(h, Wm, nullptr, nullptr, y, 128, 128, blockIdx.x * 128, 0, 0, 128);
}

__launch_bounds__(256, 2)
__global__ void ffn2_part_k(const float* __restrict__ mid, const float* __restrict__ W2,
                            float* __restrict__ p0, float* __restrict__ p1,
                            float* __restrict__ p2, float* __restrict__ p3) {
    int ks = blockIdx.z;
    float* y = (ks == 0) ? p0 : (ks == 1) ? p1 : (ks == 2) ? p2 : p3;
    gemm_body<EP_NONE>(mid, W2, nullptr, nullptr, y, 128, 512,
                       blockIdx.x * 128, 0, ks * 128, ks * 128 + 128);
}

// ---------------------------------------------------------------------------
// qkv transform: sigq = sigmoid(q) in place; Mt[b][c][i] bf16 (c-major,
// i contiguous) with rows 0..127 = exp(k)*v, rows 128..255 = exp(k).
// Tile = 64 i-rows x 128 e; 256 threads -> 32 elements per thread.
// (Round-2/3 bug: loop covered only 2048/8192 elems -> uninit LDS -> NaN.)
// ---------------------------------------------------------------------------
__global__ void qkv_transform_k(float* __restrict__ q, const float* __restrict__ k,
                                const float* __restrict__ v, ushort* __restrict__ Mt) {
    __shared__ ushort T[2][128][68];     // +4 pad
    const int t  = threadIdx.x;
    const int i0 = blockIdx.x * 64;
    const int b  = blockIdx.y;
    size_t gbase = ((size_t)b * NTOK + i0) * EDIM;
#pragma unroll 8
    for (int u = 0; u < 32; ++u) {
        int idx = u * 256 + t;           // 0..8191 over [r(64)][e(128)]
        int r = idx >> 7, e = idx & 127;
        size_t g = gbase + idx;
        float kv = k[g], vv = v[g], qq = q[g];
        float kw = __expf(kv);
        q[g] = 1.0f / (1.0f + __expf(-qq));
        T[0][e][r] = f2bf(kw * vv);
        T[1][e][r] = f2bf(kw);
    }
    __syncthreads();
    int m = t >> 7;                      // 0: kw*v, 1: kw
    int e = t & 127;
    ushort* dst = Mt + ((size_t)b * 256 + m * 128 + e) * NTOK + i0;
#pragma unroll
    for (int s4 = 0; s4 < 16; ++s4) {
        ushort4 x = *(const ushort4*)&T[m][e][s4 * 4];
        *(ushort4*)&dst[s4 * 4] = x;
    }
}

// ---------------------------------------------------------------------------
// Big GEMM (MFMA bf16): out[j,c] = sum_i exp(coef*dis[b,j,i]) * Mt[b,c,i]
// Block tile 32j x 256c, BK=32, K-split 2. 4 waves, wave tile 32x64.
// VALU staging: A fp32 load + exp + bf16 pack; B ushort8 load -> ds_write.
// LDS rows padded to 40 ushorts (80B).
// ---------------------------------------------------------------------------
__launch_bounds__(256, 2)
__global__ void big_gemm_mfma_k(const float* __restrict__ dis, const float* __restrict__ alphap,
                                const ushort* __restrict__ Mt,
                                float* __restrict__ P0, float* __restrict__ P1) {
    __shared__ ushort As[32 * 40];       // [j][i] bf16, padded
    __shared__ ushort Bs[256 * 40];      // [c][i] bf16, padded
    const int t    = threadIdx.x;
    const int lane = t & 63;
    const int wv   = t >> 6;
    const int j0   = blockIdx.x * 32;
    const int b    = blockIdx.y;
    const int s    = blockIdx.z;
    const float coef = -alphap[0] * 12.0f;          // log2(4096) = 12
    const float* disb = dis + (size_t)b * NTOK * NTOK;
    const ushort* Mtb = Mt + (size_t)b * 256 * NTOK;
    float* outp = ((s == 0) ? P0 : P1) + (size_t)b * NTOK * 256;

    f32x4 acc[2][4] = {};

    const int aj = t >> 3;               // 0..31  A row staged
    const int aq = t & 7;                // 0..7   A col quad
    const int brow = t >> 2;             // 0..63  B row staged (+p*64)
    const int bcol = (t & 3) * 8;        // B col offset (ushorts)
    const int m15 = lane & 15;
    const int kq  = (lane >> 4) * 8;     // k-offset of fragment

    const int k0 = s * (NTOK / 2);
    for (int kc = k0; kc < k0 + NTOK / 2; kc += 32) {
        // --- stage A: 32x32 fp32 -> exp -> bf16 ---
        float4 f = *(const float4*)(disb + (size_t)(j0 + aj) * NTOK + kc + aq * 4);
        ushort4 p4;
        p4.x = f2bf(__expf(coef * f.x));
        p4.y = f2bf(__expf(coef * f.y));
        p4.z = f2bf(__expf(coef * f.z));
        p4.w = f2bf(__expf(coef * f.w));
        *(ushort4*)&As[aj * 40 + aq * 4] = p4;
        // --- stage B: 256x32 bf16 via VALU, 16B per thread x 4 ---
#pragma unroll
        for (int p = 0; p < 4; ++p) {
            int row = p * 64 + brow;
            bf16x8 bv = *(const bf16x8*)&Mtb[(size_t)row * NTOK + kc + bcol];
            *(bf16x8*)&Bs[row * 40 + bcol] = bv;
        }
        __syncthreads();
        // --- compute ---
        bf16x8 af0 = *(const bf16x8*)&As[m15 * 40 + kq];
        bf16x8 af1 = *(const bf16x8*)&As[(16 + m15) * 40 + kq];
#pragma unroll
        for (int ni = 0; ni < 4; ++ni) {
            bf16x8 bfv = *(const bf16x8*)&Bs[(wv * 64 + ni * 16 + m15) * 40 + kq];
            acc[0][ni] = __builtin_amdgcn_mfma_f32_16x16x32_bf16(af0, bfv, acc[0][ni], 0, 0, 0);
            acc[1][ni] = __builtin_amdgcn_mfma_f32_16x16x32_bf16(af1, bfv, acc[1][ni], 0, 0, 0);
        }
        __syncthreads();
    }

    // epilogue: C/D map col=lane&15, row=(lane>>4)*4+reg
#pragma unroll
    for (int mi = 0; mi < 2; ++mi)
#pragma unroll
        for (int ni = 0; ni < 4; ++ni)
#pragma unroll
            for (int r = 0; r < 4; ++r) {
                int j = j0 + mi * 16 + (lane >> 4) * 4 + r;
                int c = wv * 64 + ni * 16 + m15;
                outp[(size_t)j * 256 + c] = acc[mi][ni][r];
            }
}

// ---------------------------------------------------------------------------
// attn epilogue: attn = sigmoid(q) * (w1/w2), summing the two K-split halves
// ---------------------------------------------------------------------------
__global__ void attn_ep_k(const float* __restrict__ sigq, const float* __restrict__ P0,
                          const float* __restrict__ P1, float* __restrict__ attn) {
    int idx = blockIdx.x * 256 + threadIdx.x;   // [b*N + j][e]
    int e = idx & 127;
    int r = idx >> 7;
    size_t base = (size_t)r * 256;
    float w1 = P0[base + e]       + P1[base + e];
    float w2 = P0[base + 128 + e] + P1[base + 128 + e];
    attn[idx] = sigq[idx] * (w1 / w2);
}

// final: out = out1 + b2 + p0 + p1 + p2 + p3(=d_out in place)
__global__ void final_add_k(const float* __restrict__ out1, const float* __restrict__ b2,
                            const float* __restrict__ p0, const float* __restrict__ p1,
                            const float* __restrict__ p2, float* __restrict__ outp) {
    int idx = blockIdx.x * 256 + threadIdx.x;
    int e = idx & 127;
    outp[idx] = out1[idx] + b2[e] + p0[idx] + p1[idx] + p2[idx] + outp[idx];
}

// ---------------------------------------------------------------------------
extern "C" void kernel_launch(void* const* d_in, const int* in_sizes, int n_in,
                              void* d_out, int out_size, void* d_ws, size_t ws_size,
                              hipStream_t stream) {
    const float* input1 = (const float*)d_in[0];
    const float* dis    = (const float*)d_in[1];
    const float* Wq     = (const float*)d_in[2];
    const float* Wk     = (const float*)d_in[3];
    const float* Wv     = (const float*)d_in[4];
    const float* alpha  = (const float*)d_in[5];
    const float* ln1    = (const float*)d_in[6];
    const float* ln2    = (const float*)d_in[7];
    const float* Wcomb  = (const float*)d_in[8];
    const float* W1     = (const float*)d_in[9];
    const float* b1     = (const float*)d_in[10];
    const float* W2     = (const float*)d_in[11];
    const float* b2     = (const float*)d_in[12];
    float* out = (float*)d_out;

    // workspace overlay (8M floats = 32 MiB total)
    const size_t MEG = 1u << 20;
    float* ws = (float*)d_ws;
    float* bH = ws;                 // h -> Mt(bf16) -> h2 -> ffn2 p0
    float* bQ = ws + 1 * MEG;       // q/sigq -> ffn2 p1
    float* bK = ws + 2 * MEG;       // k -> out1 (live to end)
    float* bV = ws + 3 * MEG;       // v -> attn -> ffn2 p2
    float* P0 = ws + 4 * MEG;       // big-gemm split 0 [2][4096][256]
    float* P1 = ws + 6 * MEG;       // big-gemm split 1
    ushort* Mt = (ushort*)bH;       // 2M ushorts = 4 MB (overlays bH)
    float* mid = P0;                // ffn mid [8192][512] = 16 MB (P0+P1)

    // 1) h = rmsnorm(input1, ln1)
    rmsnorm_k<<<dim3(BNROWS / 4), dim3(64, 4), 0, stream>>>(input1, ln1, bH);
    // 2) q,k,v projections
    gemm_qkv_k<<<dim3(64, 3), 256, 0, stream>>>(bH, Wq, Wk, Wv, bQ, bK, bV);
    // 3) sigq in place; Mt = [exp(k)*v | exp(k)]^T bf16
    qkv_transform_k<<<dim3(64, 2), 256, 0, stream>>>(bQ, bK, bV, Mt);
    // 4) big GEMM, MFMA bf16, K-split 2
    big_gemm_mfma_k<<<dim3(128, 2, 2), 256, 0, stream>>>(dis, alpha, Mt, P0, P1);
    // 5) attn = sigq * w1/w2
    attn_ep_k<<<dim3(4096), 256, 0, stream>>>(bQ, P0, P1, bV);
    // 6) out1 = input1 + attn @ Wcomb.T
    gemm_wt_k<EP_RESID><<<dim3(64, 1), 256, 0, stream>>>(bV, Wcomb, nullptr, input1, bK, 128, 128);
    // 7) h2 = rmsnorm(out1, ln2)
    rmsnorm_k<<<dim3(BNROWS / 4), dim3(64, 4), 0, stream>>>(bK, ln2, bH);
    // 8) mid = relu(h2 @ W1.T + b1)
    gemm_wt_k<EP_RELU_BIAS><<<dim3(64, 4), 256, 0, stream>>>(bH, W1, b1, nullptr, mid, 512, 128);
    // 9) ffn2 partials (K-split 4)
    ffn2_part_k<<<dim3(64, 1, 4), 256, 0, stream>>>(mid, W2, bH, bQ, bV, out);
    // 10) out = out1 + b2 + sum(partials)
    final_add_k<<<dim3(4096), 256, 0, stream>>>(bK, b2, bH, bQ, bV, out);
}

// Round 5
// 327.975 us; speedup vs baseline: 1.7647x; 1.1317x over previous
//
#include <hip/hip_runtime.h>
#include <hip/hip_bf16.h>

#define NTOK 4096          // N
#define BNROWS 8192        // B*N
#define EDIM 128
#define FDIM 512

typedef __attribute__((ext_vector_type(8))) short bf16x8;
typedef __attribute__((ext_vector_type(4))) float f32x4;

__device__ __forceinline__ ushort f2bf(float x) {
    union { float f; unsigned u; } c; c.f = x;
    unsigned r = c.u + 0x7FFF + ((c.u >> 16) & 1);
    return (ushort)(r >> 16);
}
__device__ __forceinline__ float bf2f(ushort x) {
    union { unsigned u; float f; } c; c.u = ((unsigned)x) << 16;
    return c.f;
}

// ---------------------------------------------------------------------------
// Weight conversion fp32 -> bf16, concatenated layout:
// Wq@0 Wk@16384 Wv@32768 Wcomb@49152 W1@65536 W2@131072  (196608 total)
// ---------------------------------------------------------------------------
__global__ void wconv_k(const float* __restrict__ Wq, const float* __restrict__ Wk,
                        const float* __restrict__ Wv, const float* __restrict__ Wc,
                        const float* __restrict__ W1, const float* __restrict__ W2,
                        ushort* __restrict__ dst) {
    int i = blockIdx.x * 256 + threadIdx.x;
    const float* src; int off;
    if (i < 16384)       { src = Wq; off = i; }
    else if (i < 32768)  { src = Wk; off = i - 16384; }
    else if (i < 49152)  { src = Wv; off = i - 32768; }
    else if (i < 65536)  { src = Wc; off = i - 49152; }
    else if (i < 131072) { src = W1; off = i - 65536; }
    else                 { src = W2; off = i - 131072; }
    dst[i] = f2bf(src[off]);
}

// ---------------------------------------------------------------------------
// RMSNorm fp32 -> bf16: one wave per row of 128
// ---------------------------------------------------------------------------
__global__ void rmsnorm_bf_k(const float* __restrict__ x, const float* __restrict__ w,
                             ushort* __restrict__ y) {
    int row  = blockIdx.x * 4 + threadIdx.y;
    int lane = threadIdx.x;
    const float2* xr = (const float2*)(x + (size_t)row * EDIM);
    float2 v = xr[lane];
    float ss = v.x * v.x + v.y * v.y;
#pragma unroll
    for (int off = 32; off > 0; off >>= 1) ss += __shfl_down(ss, off, 64);
    ss = __shfl(ss, 0, 64);
    float r = rsqrtf(ss * (1.0f / 128.0f) + 1e-6f);
    float2 wv = ((const float2*)w)[lane];
    ushort2 o; o.x = f2bf(v.x * r * wv.x); o.y = f2bf(v.y * r * wv.y);
    ((ushort2*)(y + (size_t)row * EDIM))[lane] = o;
}

// ---------------------------------------------------------------------------
// Shared bf16 MFMA GEMM body: C[r,c] = sum_k A[r,k]*B[c,k], tile 32r x 128c,
// K staged in chunks of 128. 4 waves: wave w covers cols w*32..w*32+31
// (acc[2 mi][2 ni]). LDS rows padded to 136 ushorts (272B).
// ---------------------------------------------------------------------------
#define EB_BF16   0   // out bf16
#define EB_RESID  1   // out fp32 = acc + resid
#define EB_RELUB  2   // out bf16 = relu(acc + bias)
#define EB_PART   3   // out fp32 = acc (partial)

template<int EPIL>
__device__ __forceinline__ void mgemm_body(
    const ushort* __restrict__ A, int lda,
    const ushort* __restrict__ B, int ldb,
    float* __restrict__ outF, ushort* __restrict__ outB, int Nout, int colbase,
    const float* __restrict__ bias, const float* __restrict__ resid,
    int M0, int k0, int nchunks)
{
    __shared__ ushort As[32 * 136];
    __shared__ ushort Bs[128 * 136];
    const int t = threadIdx.x, lane = t & 63, wv = t >> 6;
    const int m15 = lane & 15, kq = (lane >> 4) * 8;
    const int c0w = wv * 32;
    f32x4 acc[2][2] = {};

    const int ar = t >> 3;            // 0..31
    const int as0 = (t & 7) * 2;      // 2 segs of 8 ushorts
    const int br = t >> 1;            // 0..127
    const int bs0 = (t & 1) * 8;      // 8 segs

    for (int c = 0; c < nchunks; ++c) {
        if (c) __syncthreads();
        int kb = k0 + c * 128;
#pragma unroll
        for (int j = 0; j < 2; ++j) {
            int seg = as0 + j;
            *(bf16x8*)&As[ar * 136 + seg * 8] =
                *(const bf16x8*)&A[(size_t)(M0 + ar) * lda + kb + seg * 8];
        }
#pragma unroll
        for (int j = 0; j < 8; ++j) {
            int seg = bs0 + j;
            *(bf16x8*)&Bs[br * 136 + seg * 8] =
                *(const bf16x8*)&B[(size_t)br * ldb + kb + seg * 8];
        }
        __syncthreads();
#pragma unroll
        for (int kc = 0; kc < 4; ++kc) {
            int ko = kc * 32 + kq;
            bf16x8 a0 = *(const bf16x8*)&As[m15 * 136 + ko];
            bf16x8 a1 = *(const bf16x8*)&As[(16 + m15) * 136 + ko];
            bf16x8 b0 = *(const bf16x8*)&Bs[(c0w + m15) * 136 + ko];
            bf16x8 b1 = *(const bf16x8*)&Bs[(c0w + 16 + m15) * 136 + ko];
            acc[0][0] = __builtin_amdgcn_mfma_f32_16x16x32_bf16(a0, b0, acc[0][0], 0, 0, 0);
            acc[0][1] = __builtin_amdgcn_mfma_f32_16x16x32_bf16(a0, b1, acc[0][1], 0, 0, 0);
            acc[1][0] = __builtin_amdgcn_mfma_f32_16x16x32_bf16(a1, b0, acc[1][0], 0, 0, 0);
            acc[1][1] = __builtin_amdgcn_mfma_f32_16x16x32_bf16(a1, b1, acc[1][1], 0, 0, 0);
        }
    }
    // epilogue: C/D map col=lane&15, row=(lane>>4)*4+reg
#pragma unroll
    for (int mi = 0; mi < 2; ++mi)
#pragma unroll
        for (int ni = 0; ni < 2; ++ni)
#pragma unroll
            for (int r = 0; r < 4; ++r) {
                int row = M0 + mi * 16 + (lane >> 4) * 4 + r;
                int lc  = c0w + ni * 16 + m15;
                size_t off = (size_t)row * Nout + colbase + lc;
                float vv = acc[mi][ni][r];
                if (EPIL == EB_BF16)  outB[off] = f2bf(vv);
                if (EPIL == EB_RESID) outF[off] = vv + resid[off];
                if (EPIL == EB_RELUB) outB[off] = f2bf(fmaxf(vv + bias[lc], 0.0f));
                if (EPIL == EB_PART)  outF[off] = vv;
            }
}

__launch_bounds__(256, 3)
__global__ void qkv_mfma_k(const ushort* __restrict__ h, const ushort* __restrict__ Wbf,
                           ushort* __restrict__ qb, ushort* __restrict__ kb,
                           ushort* __restrict__ vb) {
    int sel = blockIdx.y;
    const ushort* B = Wbf + sel * 16384;
    ushort* out = (sel == 0) ? qb : (sel == 1) ? kb : vb;
    mgemm_body<EB_BF16>(h, 128, B, 128, nullptr, out, 128, 0, nullptr, nullptr,
                        blockIdx.x * 32, 0, 1);
}

__launch_bounds__(256, 3)
__global__ void wcomb_mfma_k(const ushort* __restrict__ attn, const ushort* __restrict__ Wbf,
                             const float* __restrict__ resid, float* __restrict__ out1) {
    mgemm_body<EB_RESID>(attn, 128, Wbf + 49152, 128, out1, nullptr, 128, 0,
                         nullptr, resid, blockIdx.x * 32, 0, 1);
}

__launch_bounds__(256, 3)
__global__ void ffn1_mfma_k(const ushort* __restrict__ h2, const ushort* __restrict__ Wbf,
                            const float* __restrict__ b1, ushort* __restrict__ mid) {
    int N0 = blockIdx.y * 128;
    mgemm_body<EB_RELUB>(h2, 128, Wbf + 65536 + N0 * 128, 128, nullptr, mid, 512, N0,
                         b1 + N0, nullptr, blockIdx.x * 32, 0, 1);
}

__launch_bounds__(256, 3)
__global__ void ffn2_mfma_k(const ushort* __restrict__ mid, const ushort* __restrict__ Wbf,
                            float* __restrict__ p0, float* __restrict__ p1) {
    int ks = blockIdx.y;
    mgemm_body<EB_PART>(mid, 512, Wbf + 131072, 512, ks ? p1 : p0, nullptr, 128, 0,
                        nullptr, nullptr, blockIdx.x * 32, ks * 256, 2);
}

// ---------------------------------------------------------------------------
// qkv transform: sigq(fp32) = sigmoid(q); Mt[b][c][i] bf16, rows 0..127 =
// exp(k)*v, rows 128..255 = exp(k). Inputs bf16.
// ---------------------------------------------------------------------------
__global__ void qkv_transform_k(const ushort* __restrict__ qb, const ushort* __restrict__ kb,
                                const ushort* __restrict__ vb,
                                float* __restrict__ sigq, ushort* __restrict__ Mt) {
    __shared__ ushort T[2][128][68];
    const int t  = threadIdx.x;
    const int i0 = blockIdx.x * 64;
    const int b  = blockIdx.y;
    size_t gbase = ((size_t)b * NTOK + i0) * EDIM;
#pragma unroll 8
    for (int u = 0; u < 32; ++u) {
        int idx = u * 256 + t;           // 0..8191 over [r(64)][e(128)]
        int r = idx >> 7, e = idx & 127;
        size_t g = gbase + idx;
        float kv = bf2f(kb[g]), vv = bf2f(vb[g]), qq = bf2f(qb[g]);
        float kw = __expf(kv);
        sigq[g] = 1.0f / (1.0f + __expf(-qq));
        T[0][e][r] = f2bf(kw * vv);
        T[1][e][r] = f2bf(kw);
    }
    __syncthreads();
    int m = t >> 7;
    int e = t & 127;
    ushort* dst = Mt + ((size_t)b * 256 + m * 128 + e) * NTOK + i0;
#pragma unroll
    for (int s4 = 0; s4 < 16; ++s4) {
        ushort4 x = *(const ushort4*)&T[m][e][s4 * 4];
        *(ushort4*)&dst[s4 * 4] = x;
    }
}

// ---------------------------------------------------------------------------
// Big GEMM (MFMA bf16): out[j,c] = sum_i exp(coef*dis[b,j,i]) * Mt[b,c,i]
// Tile 32j x 256c, BK=64, K-split 2, 1-deep register prefetch.
// LDS rows padded to 72 ushorts (144B).
// ---------------------------------------------------------------------------
__launch_bounds__(256, 2)
__global__ void big_gemm_mfma_k(const float* __restrict__ dis, const float* __restrict__ alphap,
                                const ushort* __restrict__ Mt,
                                float* __restrict__ P0, float* __restrict__ P1) {
    __shared__ ushort As[32 * 72];
    __shared__ ushort Bs[256 * 72];
    const int t = threadIdx.x, lane = t & 63, wv = t >> 6;
    const int j0 = blockIdx.x * 32;
    const int b  = blockIdx.y;
    const int s  = blockIdx.z;
    const float coef = -alphap[0] * 12.0f;          // log2(4096) = 12
    const float* disb = dis + (size_t)b * NTOK * NTOK;
    const ushort* Mtb = Mt + (size_t)b * 256 * NTOK;
    float* outp = ((s == 0) ? P0 : P1) + (size_t)b * NTOK * 256;

    f32x4 acc[2][4] = {};
    const int aj = t >> 3;           // 0..31 A row staged
    const int ak = (t & 7) * 8;      // A col offset (8 floats)
    const int m15 = lane & 15, kq = (lane >> 4) * 8;
    const int k0 = s * (NTOK / 2);
    const int nIter = (NTOK / 2) / 64;   // 32

    float4 fa[2][2];
    bf16x8 pb[2][8];
    {   // preload iter 0
        const float* ap = disb + (size_t)(j0 + aj) * NTOK + k0 + ak;
        fa[0][0] = *(const float4*)ap;
        fa[0][1] = *(const float4*)(ap + 4);
        const ushort* bp = Mtb + (size_t)t * NTOK + k0;
#pragma unroll
        for (int u = 0; u < 8; ++u) pb[0][u] = *(const bf16x8*)(bp + u * 8);
    }

#pragma unroll 2
    for (int it = 0; it < nIter; ++it) {
        const int cur = it & 1, nxt = cur ^ 1;
        // pack + write current A
        bf16x8 a8;
        a8[0] = (short)f2bf(__expf(coef * fa[cur][0].x));
        a8[1] = (short)f2bf(__expf(coef * fa[cur][0].y));
        a8[2] = (short)f2bf(__expf(coef * fa[cur][0].z));
        a8[3] = (short)f2bf(__expf(coef * fa[cur][0].w));
        a8[4] = (short)f2bf(__expf(coef * fa[cur][1].x));
        a8[5] = (short)f2bf(__expf(coef * fa[cur][1].y));
        a8[6] = (short)f2bf(__expf(coef * fa[cur][1].z));
        a8[7] = (short)f2bf(__expf(coef * fa[cur][1].w));
        *(bf16x8*)&As[aj * 72 + ak] = a8;
#pragma unroll
        for (int u = 0; u < 8; ++u) *(bf16x8*)&Bs[t * 72 + u * 8] = pb[cur][u];
        __syncthreads();
        // issue next iteration's global loads (prefetch)
        if (it + 1 < nIter) {
            int kn = k0 + (it + 1) * 64;
            const float* ap = disb + (size_t)(j0 + aj) * NTOK + kn + ak;
            fa[nxt][0] = *(const float4*)ap;
            fa[nxt][1] = *(const float4*)(ap + 4);
            const ushort* bp = Mtb + (size_t)t * NTOK + kn;
#pragma unroll
            for (int u = 0; u < 8; ++u) pb[nxt][u] = *(const bf16x8*)(bp + u * 8);
        }
        // compute from LDS
#pragma unroll
        for (int kh = 0; kh < 2; ++kh) {
            int ko = kh * 32 + kq;
            bf16x8 a0 = *(const bf16x8*)&As[m15 * 72 + ko];
            bf16x8 a1 = *(const bf16x8*)&As[(16 + m15) * 72 + ko];
#pragma unroll
            for (int ni = 0; ni < 4; ++ni) {
                bf16x8 bv = *(const bf16x8*)&Bs[(wv * 64 + ni * 16 + m15) * 72 + ko];
                acc[0][ni] = __builtin_amdgcn_mfma_f32_16x16x32_bf16(a0, bv, acc[0][ni], 0, 0, 0);
                acc[1][ni] = __builtin_amdgcn_mfma_f32_16x16x32_bf16(a1, bv, acc[1][ni], 0, 0, 0);
            }
        }
        __syncthreads();
    }

    // epilogue: C/D map col=lane&15, row=(lane>>4)*4+reg
#pragma unroll
    for (int mi = 0; mi < 2; ++mi)
#pragma unroll
        for (int ni = 0; ni < 4; ++ni)
#pragma unroll
            for (int r = 0; r < 4; ++r) {
                int j = j0 + mi * 16 + (lane >> 4) * 4 + r;
                int c = wv * 64 + ni * 16 + m15;
                outp[(size_t)j * 256 + c] = acc[mi][ni][r];
            }
}

// ---------------------------------------------------------------------------
// attn epilogue: attn(bf16) = sigmoid(q) * (w1/w2), sum of K-split halves
// ---------------------------------------------------------------------------
__global__ void attn_ep_k(const float* __restrict__ sigq, const float* __restrict__ P0,
                          const float* __restrict__ P1, ushort* __restrict__ attn) {
    int idx = blockIdx.x * 256 + threadIdx.x;
    int e = idx & 127;
    int r = idx >> 7;
    size_t base = (size_t)r * 256;
    float w1 = P0[base + e]       + P1[base + e];
    float w2 = P0[base + 128 + e] + P1[base + 128 + e];
    attn[idx] = f2bf(sigq[idx] * (w1 / w2));
}

// final: out = out1 + b2 + p1 + outp(=part0 in place)
__global__ void final_add_k(const float* __restrict__ out1, const float* __restrict__ b2,
                            const float* __restrict__ p1, float* __restrict__ outp) {
    int idx = blockIdx.x * 256 + threadIdx.x;
    int e = idx & 127;
    outp[idx] = out1[idx] + b2[e] + p1[idx] + outp[idx];
}

// ---------------------------------------------------------------------------
extern "C" void kernel_launch(void* const* d_in, const int* in_sizes, int n_in,
                              void* d_out, int out_size, void* d_ws, size_t ws_size,
                              hipStream_t stream) {
    const float* input1 = (const float*)d_in[0];
    const float* dis    = (const float*)d_in[1];
    const float* Wq     = (const float*)d_in[2];
    const float* Wk     = (const float*)d_in[3];
    const float* Wv     = (const float*)d_in[4];
    const float* alpha  = (const float*)d_in[5];
    const float* ln1    = (const float*)d_in[6];
    const float* ln2    = (const float*)d_in[7];
    const float* Wcomb  = (const float*)d_in[8];
    const float* W1     = (const float*)d_in[9];
    const float* b1     = (const float*)d_in[10];
    const float* W2     = (const float*)d_in[11];
    const float* b2     = (const float*)d_in[12];
    float* out = (float*)d_out;

    // workspace overlay (byte offsets; peak 31 MiB)
    char* w8 = (char*)d_ws;
    float*  P0    = (float*)(w8);                   // [0,8M)   phase 5-6
    float*  P1    = (float*)(w8 + (8u << 20));      // [8,16M)  phase 5-6
    ushort* h_bf  = (ushort*)(w8);                  // [0,2M)   phase 2-3
    ushort* q_bf  = (ushort*)(w8 + (16u << 20));    // [16,18M) phase 3-4
    ushort* k_bf  = (ushort*)(w8 + (18u << 20));    // [18,20M) phase 3-4
    ushort* v_bf  = (ushort*)(w8 + (20u << 20));    // [20,22M) phase 3-4
    ushort* Mt    = (ushort*)(w8 + (22u << 20));    // [22,26M) phase 4-5
    ushort* Wbf   = (ushort*)(w8 + (26u << 20));    // [26,26.4M) all phases
    float*  sigq  = (float*)(w8 + (27u << 20));     // [27,31M) phase 4-6
    float*  out1  = (float*)(w8 + (27u << 20));     // [27,31M) phase 7-end (sigq dead)
    ushort* attn  = (ushort*)(w8 + (18u << 20));    // [18,20M) phase 6-7 (k_bf dead)
    ushort* h2_bf = (ushort*)(w8 + (16u << 20));    // [16,18M) phase 8-9 (q_bf dead)
    ushort* mid   = (ushort*)(w8 + (8u << 20));     // [8,16M)  phase 9-10 (P1 dead)
    float*  part1 = (float*)(w8);                   // [0,4M)   phase 10-11 (P0 dead)

    // 1) weights -> bf16
    wconv_k<<<dim3(768), 256, 0, stream>>>(Wq, Wk, Wv, Wcomb, W1, W2, Wbf);
    // 2) h = rmsnorm(input1, ln1) -> bf16
    rmsnorm_bf_k<<<dim3(BNROWS / 4), dim3(64, 4), 0, stream>>>(input1, ln1, h_bf);
    // 3) q,k,v projections (bf16 MFMA)
    qkv_mfma_k<<<dim3(256, 3), 256, 0, stream>>>(h_bf, Wbf, q_bf, k_bf, v_bf);
    // 4) sigq fp32; Mt = [exp(k)*v | exp(k)]^T bf16
    qkv_transform_k<<<dim3(64, 2), 256, 0, stream>>>(q_bf, k_bf, v_bf, sigq, Mt);
    // 5) big GEMM, MFMA bf16, K-split 2, prefetched
    big_gemm_mfma_k<<<dim3(128, 2, 2), 256, 0, stream>>>(dis, alpha, Mt, P0, P1);
    // 6) attn = sigq * w1/w2 -> bf16
    attn_ep_k<<<dim3(4096), 256, 0, stream>>>(sigq, P0, P1, attn);
    // 7) out1 = input1 + attn @ Wcomb.T (fp32)
    wcomb_mfma_k<<<dim3(256), 256, 0, stream>>>(attn, Wbf, input1, out1);
    // 8) h2 = rmsnorm(out1, ln2) -> bf16
    rmsnorm_bf_k<<<dim3(BNROWS / 4), dim3(64, 4), 0, stream>>>(out1, ln2, h2_bf);
    // 9) mid = relu(h2 @ W1.T + b1) -> bf16
    ffn1_mfma_k<<<dim3(256, 4), 256, 0, stream>>>(h2_bf, Wbf, b1, mid);
    // 10) ffn2 partials (K-split 2): part0 -> d_out, part1 -> scratch
    ffn2_mfma_k<<<dim3(256, 2), 256, 0, stream>>>(mid, Wbf, out, part1);
    // 11) out = out1 + b2 + part1 + part0
    final_add_k<<<dim3(4096), 256, 0, stream>>>(out1, b2, part1, out);
}

// Round 6
// 268.107 us; speedup vs baseline: 2.1587x; 1.2233x over previous
//
#include <hip/hip_runtime.h>

#define NTOK 4096          // N
#define BNROWS 8192        // B*N
#define EDIM 128
#define FDIM 512

typedef __attribute__((ext_vector_type(8))) short bf16x8;
typedef __attribute__((ext_vector_type(4))) float f32x4;

__device__ __forceinline__ ushort f2bf(float x) {
    union { float f; unsigned u; } c; c.f = x;
    unsigned r = c.u + 0x7FFF + ((c.u >> 16) & 1);
    return (ushort)(r >> 16);
}

// ---------------------------------------------------------------------------
// prep: blocks [0,768): weights fp32->bf16 concat (Wq@0 Wk@16384 Wv@32768
// Wcomb@49152 W1@65536 W2@131072). blocks [768,2816): rmsnorm(input1,ln1)->bf16
// ---------------------------------------------------------------------------
__global__ void prep_k(const float* __restrict__ Wq, const float* __restrict__ Wk,
                       const float* __restrict__ Wv, const float* __restrict__ Wc,
                       const float* __restrict__ W1, const float* __restrict__ W2,
                       ushort* __restrict__ Wbf,
                       const float* __restrict__ input1, const float* __restrict__ ln1w,
                       ushort* __restrict__ h_bf) {
    const int bx = blockIdx.x, t = threadIdx.x;
    if (bx < 768) {
        int i = bx * 256 + t;
        const float* src; int off;
        if (i < 16384)       { src = Wq; off = i; }
        else if (i < 32768)  { src = Wk; off = i - 16384; }
        else if (i < 49152)  { src = Wv; off = i - 32768; }
        else if (i < 65536)  { src = Wc; off = i - 49152; }
        else if (i < 131072) { src = W1; off = i - 65536; }
        else                 { src = W2; off = i - 131072; }
        Wbf[i] = f2bf(src[off]);
    } else {
        int row  = (bx - 768) * 4 + (t >> 6);
        int lane = t & 63;
        float2 v = ((const float2*)(input1 + (size_t)row * EDIM))[lane];
        float ss = v.x * v.x + v.y * v.y;
#pragma unroll
        for (int off = 32; off > 0; off >>= 1) ss += __shfl_down(ss, off, 64);
        ss = __shfl(ss, 0, 64);
        float r = rsqrtf(ss * (1.0f / 128.0f) + 1e-6f);
        float2 wv = ((const float2*)ln1w)[lane];
        ushort2 o; o.x = f2bf(v.x * r * wv.x); o.y = f2bf(v.y * r * wv.y);
        ((ushort2*)(h_bf + (size_t)row * EDIM))[lane] = o;
    }
}

// ---------------------------------------------------------------------------
// Shared bf16 MFMA GEMM body: tile 32r x 128c, K in chunks of 128.
// ---------------------------------------------------------------------------
#define EB_SIGQ  0   // outF = sigmoid(acc)
#define EB_RELUB 1   // outB = bf16(relu(acc + bias))
#define EB_ACC   2   // outF += acc

template<int EPIL>
__device__ __forceinline__ void mgemm_body(
    const ushort* __restrict__ A, int lda,
    const ushort* __restrict__ B, int ldb,
    float* __restrict__ outF, ushort* __restrict__ outB, int Nout, int colbase,
    const float* __restrict__ bias, int M0, int nchunks)
{
    __shared__ ushort As[32 * 136];
    __shared__ ushort Bs[128 * 136];
    const int t = threadIdx.x, lane = t & 63, wv = t >> 6;
    const int m15 = lane & 15, kq = (lane >> 4) * 8;
    const int c0w = wv * 32;
    f32x4 acc[2][2] = {};

    const int ar = t >> 3, as0 = (t & 7) * 2;
    const int br = t >> 1, bs0 = (t & 1) * 8;

    for (int c = 0; c < nchunks; ++c) {
        if (c) __syncthreads();
        int kb = c * 128;
#pragma unroll
        for (int j = 0; j < 2; ++j) {
            int seg = as0 + j;
            *(bf16x8*)&As[ar * 136 + seg * 8] =
                *(const bf16x8*)&A[(size_t)(M0 + ar) * lda + kb + seg * 8];
        }
#pragma unroll
        for (int j = 0; j < 8; ++j) {
            int seg = bs0 + j;
            *(bf16x8*)&Bs[br * 136 + seg * 8] =
                *(const bf16x8*)&B[(size_t)br * ldb + kb + seg * 8];
        }
        __syncthreads();
#pragma unroll
        for (int kc = 0; kc < 4; ++kc) {
            int ko = kc * 32 + kq;
            bf16x8 a0 = *(const bf16x8*)&As[m15 * 136 + ko];
            bf16x8 a1 = *(const bf16x8*)&As[(16 + m15) * 136 + ko];
            bf16x8 b0 = *(const bf16x8*)&Bs[(c0w + m15) * 136 + ko];
            bf16x8 b1 = *(const bf16x8*)&Bs[(c0w + 16 + m15) * 136 + ko];
            acc[0][0] = __builtin_amdgcn_mfma_f32_16x16x32_bf16(a0, b0, acc[0][0], 0, 0, 0);
            acc[0][1] = __builtin_amdgcn_mfma_f32_16x16x32_bf16(a0, b1, acc[0][1], 0, 0, 0);
            acc[1][0] = __builtin_amdgcn_mfma_f32_16x16x32_bf16(a1, b0, acc[1][0], 0, 0, 0);
            acc[1][1] = __builtin_amdgcn_mfma_f32_16x16x32_bf16(a1, b1, acc[1][1], 0, 0, 0);
        }
    }
#pragma unroll
    for (int mi = 0; mi < 2; ++mi)
#pragma unroll
        for (int ni = 0; ni < 2; ++ni)
#pragma unroll
            for (int r = 0; r < 4; ++r) {
                int row = M0 + mi * 16 + (lane >> 4) * 4 + r;
                int lc  = c0w + ni * 16 + m15;
                size_t off = (size_t)row * Nout + colbase + lc;
                float vv = acc[mi][ni][r];
                if (EPIL == EB_SIGQ)  outF[off] = 1.0f / (1.0f + __expf(-vv));
                if (EPIL == EB_RELUB) outB[off] = f2bf(fmaxf(vv + bias[lc], 0.0f));
                if (EPIL == EB_ACC)   outF[off] += vv;
            }
}

__launch_bounds__(256, 3)
__global__ void q_sig_k(const ushort* __restrict__ h, const ushort* __restrict__ Wbf,
                        float* __restrict__ sigq) {
    mgemm_body<EB_SIGQ>(h, 128, Wbf, 128, sigq, nullptr, 128, 0, nullptr,
                        blockIdx.x * 32, 1);
}

__launch_bounds__(256, 3)
__global__ void ffn1_k(const ushort* __restrict__ h2, const ushort* __restrict__ Wbf,
                       const float* __restrict__ b1, ushort* __restrict__ mid) {
    int N0 = blockIdx.y * 128;
    mgemm_body<EB_RELUB>(h2, 128, Wbf + 65536 + N0 * 128, 128, nullptr, mid, 512, N0,
                         b1 + N0, blockIdx.x * 32, 1);
}

__launch_bounds__(256, 3)
__global__ void ffn2_k(const ushort* __restrict__ mid, const ushort* __restrict__ Wbf,
                       float* __restrict__ outp) {
    mgemm_body<EB_ACC>(mid, 512, Wbf + 131072, 512, outp, nullptr, 128, 0, nullptr,
                       blockIdx.x * 32, 4);
}

// ---------------------------------------------------------------------------
// k/v fused GEMM writing Mt directly (transposed, exp applied in fp32):
// Mt[b][e][i] = exp(k[i,e])*v[i,e], Mt[b][128+e][i] = exp(k[i,e]).
// Block: 32 i-rows x 64 e-cols, both mats. Grid (256, 2).
// ---------------------------------------------------------------------------
__launch_bounds__(256, 3)
__global__ void kv_mt_k(const ushort* __restrict__ h, const ushort* __restrict__ Wbf,
                        ushort* __restrict__ Mt) {
    __shared__ ushort As[32 * 136];
    __shared__ ushort Bs[2][64 * 136];
    const int t = threadIdx.x, lane = t & 63, wv = t >> 6;
    const int m15 = lane & 15, quad = lane >> 4, kq = quad * 8;
    const int M0 = blockIdx.x * 32;
    const int e0 = blockIdx.y * 64;

    const int ar = t >> 3, as0 = (t & 7) * 2;
#pragma unroll
    for (int j = 0; j < 2; ++j) {
        int seg = as0 + j;
        *(bf16x8*)&As[ar * 136 + seg * 8] =
            *(const bf16x8*)&h[(size_t)(M0 + ar) * 128 + seg * 8];
    }
    const int bm = t >> 7;               // 0: Wk, 1: Wv
    const int br = (t & 127) >> 1, bs0 = (t & 1) * 8;
    const ushort* W = Wbf + 16384 + bm * 16384;   // Wk@16384, Wv@32768
#pragma unroll
    for (int j = 0; j < 8; ++j) {
        int seg = bs0 + j;
        *(bf16x8*)&Bs[bm][br * 136 + seg * 8] =
            *(const bf16x8*)&W[(size_t)(e0 + br) * 128 + seg * 8];
    }
    __syncthreads();

    f32x4 acck[2] = {}, accv[2] = {};
    const int cw = wv * 16;
#pragma unroll
    for (int kc = 0; kc < 4; ++kc) {
        int ko = kc * 32 + kq;
        bf16x8 a0 = *(const bf16x8*)&As[m15 * 136 + ko];
        bf16x8 a1 = *(const bf16x8*)&As[(16 + m15) * 136 + ko];
        bf16x8 bk = *(const bf16x8*)&Bs[0][(cw + m15) * 136 + ko];
        bf16x8 bv = *(const bf16x8*)&Bs[1][(cw + m15) * 136 + ko];
        acck[0] = __builtin_amdgcn_mfma_f32_16x16x32_bf16(a0, bk, acck[0], 0, 0, 0);
        acck[1] = __builtin_amdgcn_mfma_f32_16x16x32_bf16(a1, bk, acck[1], 0, 0, 0);
        accv[0] = __builtin_amdgcn_mfma_f32_16x16x32_bf16(a0, bv, accv[0], 0, 0, 0);
        accv[1] = __builtin_amdgcn_mfma_f32_16x16x32_bf16(a1, bv, accv[1], 0, 0, 0);
    }
    // epilogue: rows i = M0+mi*16+quad*4+r (r consecutive), col e = e0+cw+m15
    const int b  = M0 >> 12;
    const int i0 = M0 & (NTOK - 1);
    const int e  = e0 + cw + m15;
    ushort* mt0 = Mt + ((size_t)b * 256 + e) * NTOK;         // exp(k)*v row
    ushort* mt1 = Mt + ((size_t)b * 256 + 128 + e) * NTOK;   // exp(k) row
#pragma unroll
    for (int mi = 0; mi < 2; ++mi) {
        int ib = i0 + mi * 16 + quad * 4;
        ushort4 pv, pk;
        float kw0 = __expf(acck[mi][0]); pv.x = f2bf(kw0 * accv[mi][0]); pk.x = f2bf(kw0);
        float kw1 = __expf(acck[mi][1]); pv.y = f2bf(kw1 * accv[mi][1]); pk.y = f2bf(kw1);
        float kw2 = __expf(acck[mi][2]); pv.z = f2bf(kw2 * accv[mi][2]); pk.z = f2bf(kw2);
        float kw3 = __expf(acck[mi][3]); pv.w = f2bf(kw3 * accv[mi][3]); pk.w = f2bf(kw3);
        *(ushort4*)&mt0[ib] = pv;
        *(ushort4*)&mt1[ib] = pk;
    }
}

// ---------------------------------------------------------------------------
// Big GEMM: P[b,j,c] = sum_i exp(coef*dis[b,j,i]) * Mt[b,c,i]
// Tile 32j x 256c, BK=64, K-split 2 -> grid (128,2,2)=512 blocks.
// Light staging regs (A 8 + B 32 VGPR) loaded right after the barrier of the
// PREVIOUS iteration -> one-compute-phase window; BW-saturating in aggregate.
// ---------------------------------------------------------------------------
__launch_bounds__(256, 2)
__global__ void big_gemm_k(const float* __restrict__ dis, const float* __restrict__ alphap,
                           const ushort* __restrict__ Mt,
                           float* __restrict__ P0, float* __restrict__ P1) {
    __shared__ ushort As[32 * 72];       // rows padded to 144B (2-way banks, free)
    __shared__ ushort Bs[256 * 72];
    const int t = threadIdx.x, lane = t & 63, wv = t >> 6;
    const int m15 = lane & 15, quad = lane >> 4, kq = quad * 8;
    const int j0 = blockIdx.x * 32;
    const int b  = blockIdx.y;
    const int s  = blockIdx.z;
    const float coef = -alphap[0] * 12.0f;   // log2(4096) = 12
    const float* disb = dis + (size_t)b * NTOK * NTOK;
    const ushort* Mtb = Mt + (size_t)b * 256 * NTOK;
    float* outp = ((s == 0) ? P0 : P1) + (size_t)b * NTOK * 256;

    f32x4 acc[2][4] = {};
    const int aj = t >> 3, ak = (t & 7) * 8;     // A: row, col-offset (8 floats)
    const int brow = t >> 3, bseg = (t & 7) * 8; // B: 8 p-rows, 8-ushort seg
    const int k0 = s * (NTOK / 2);

    float4 fa0, fa1;
    bf16x8 pb[8];
    {   // preload iter 0
        const float* ap = disb + (size_t)(j0 + aj) * NTOK + k0 + ak;
        fa0 = *(const float4*)ap; fa1 = *(const float4*)(ap + 4);
#pragma unroll
        for (int p = 0; p < 8; ++p)
            pb[p] = *(const bf16x8*)&Mtb[(size_t)(p * 32 + brow) * NTOK + k0 + bseg];
    }

    for (int it = 0; it < 32; ++it) {
        // regs -> LDS
        bf16x8 a8;
        a8[0] = (short)f2bf(__expf(coef * fa0.x));
        a8[1] = (short)f2bf(__expf(coef * fa0.y));
        a8[2] = (short)f2bf(__expf(coef * fa0.z));
        a8[3] = (short)f2bf(__expf(coef * fa0.w));
        a8[4] = (short)f2bf(__expf(coef * fa1.x));
        a8[5] = (short)f2bf(__expf(coef * fa1.y));
        a8[6] = (short)f2bf(__expf(coef * fa1.z));
        a8[7] = (short)f2bf(__expf(coef * fa1.w));
        *(bf16x8*)&As[aj * 72 + ak] = a8;
#pragma unroll
        for (int p = 0; p < 8; ++p)
            *(bf16x8*)&Bs[(p * 32 + brow) * 72 + bseg] = pb[p];
        __syncthreads();
        // issue next iter's loads (window = compute phase below)
        if (it < 31) {
            int kn = k0 + (it + 1) * 64;
            const float* ap = disb + (size_t)(j0 + aj) * NTOK + kn + ak;
            fa0 = *(const float4*)ap; fa1 = *(const float4*)(ap + 4);
#pragma unroll
            for (int p = 0; p < 8; ++p)
                pb[p] = *(const bf16x8*)&Mtb[(size_t)(p * 32 + brow) * NTOK + kn + bseg];
        }
        // compute
#pragma unroll
        for (int kh = 0; kh < 2; ++kh) {
            int ko = kh * 32 + kq;
            bf16x8 a0 = *(const bf16x8*)&As[m15 * 72 + ko];
            bf16x8 a1 = *(const bf16x8*)&As[(16 + m15) * 72 + ko];
#pragma unroll
            for (int ni = 0; ni < 4; ++ni) {
                bf16x8 bv = *(const bf16x8*)&Bs[(wv * 64 + ni * 16 + m15) * 72 + ko];
                acc[0][ni] = __builtin_amdgcn_mfma_f32_16x16x32_bf16(a0, bv, acc[0][ni], 0, 0, 0);
                acc[1][ni] = __builtin_amdgcn_mfma_f32_16x16x32_bf16(a1, bv, acc[1][ni], 0, 0, 0);
            }
        }
        __syncthreads();
    }
#pragma unroll
    for (int mi = 0; mi < 2; ++mi)
#pragma unroll
        for (int ni = 0; ni < 4; ++ni)
#pragma unroll
            for (int r = 0; r < 4; ++r) {
                int j = j0 + mi * 16 + quad * 4 + r;
                int c = wv * 64 + ni * 16 + m15;
                outp[(size_t)j * 256 + c] = acc[mi][ni][r];
            }
}

// ---------------------------------------------------------------------------
// Wcomb fused: A = attn = sigq*(w1/w2) computed during staging; GEMM x Wcomb;
// epilogue: out1 = acc + input1 (kept in LDS), d_out = out1 + b2,
// then in-block rmsnorm(out1, ln2) -> h2_bf.  Grid 256 (32 rows, full 128 c).
// ---------------------------------------------------------------------------
__launch_bounds__(256, 2)
__global__ void wcomb_rms2_k(const float* __restrict__ sigq,
                             const float* __restrict__ P0, const float* __restrict__ P1,
                             const ushort* __restrict__ Wbf,
                             const float* __restrict__ input1, const float* __restrict__ b2,
                             const float* __restrict__ ln2w,
                             float* __restrict__ outD, ushort* __restrict__ h2) {
    __shared__ ushort As[32 * 136];
    __shared__ ushort Bs[128 * 136];
    __shared__ float  O[32][132];
    const int t = threadIdx.x, lane = t & 63, wv = t >> 6;
    const int m15 = lane & 15, quad = lane >> 4, kq = quad * 8;
    const int M0 = blockIdx.x * 32;

    // A staging: attn[g, e] for row ar, cols e0..e0+15
    {
        const int ar = t >> 3, e0 = (t & 7) * 16;
        const int g = M0 + ar;
        const float4* sg = (const float4*)(sigq + (size_t)g * 128 + e0);
        const float4* p0a = (const float4*)(P0 + (size_t)g * 256 + e0);
        const float4* p1a = (const float4*)(P1 + (size_t)g * 256 + e0);
        const float4* p0b = (const float4*)(P0 + (size_t)g * 256 + 128 + e0);
        const float4* p1b = (const float4*)(P1 + (size_t)g * 256 + 128 + e0);
#pragma unroll
        for (int i = 0; i < 4; ++i) {
            float4 s = sg[i];
            float4 u0 = p0a[i], u1 = p1a[i], d0 = p0b[i], d1 = p1b[i];
            ushort4 a;
            a.x = f2bf(s.x * (u0.x + u1.x) / (d0.x + d1.x));
            a.y = f2bf(s.y * (u0.y + u1.y) / (d0.y + d1.y));
            a.z = f2bf(s.z * (u0.z + u1.z) / (d0.z + d1.z));
            a.w = f2bf(s.w * (u0.w + u1.w) / (d0.w + d1.w));
            *(ushort4*)&As[ar * 136 + e0 + i * 4] = a;
        }
    }
    {   // B staging: Wcomb bf16 [128][128]
        const int br = t >> 1, bs0 = (t & 1) * 8;
        const ushort* W = Wbf + 49152;
#pragma unroll
        for (int j = 0; j < 8; ++j) {
            int seg = bs0 + j;
            *(bf16x8*)&Bs[br * 136 + seg * 8] =
                *(const bf16x8*)&W[(size_t)br * 128 + seg * 8];
        }
    }
    __syncthreads();

    f32x4 acc[2][2] = {};
    const int c0w = wv * 32;
#pragma unroll
    for (int kc = 0; kc < 4; ++kc) {
        int ko = kc * 32 + kq;
        bf16x8 a0 = *(const bf16x8*)&As[m15 * 136 + ko];
        bf16x8 a1 = *(const bf16x8*)&As[(16 + m15) * 136 + ko];
        bf16x8 b0 = *(const bf16x8*)&Bs[(c0w + m15) * 136 + ko];
        bf16x8 b1 = *(const bf16x8*)&Bs[(c0w + 16 + m15) * 136 + ko];
        acc[0][0] = __builtin_amdgcn_mfma_f32_16x16x32_bf16(a0, b0, acc[0][0], 0, 0, 0);
        acc[0][1] = __builtin_amdgcn_mfma_f32_16x16x32_bf16(a0, b1, acc[0][1], 0, 0, 0);
        acc[1][0] = __builtin_amdgcn_mfma_f32_16x16x32_bf16(a1, b0, acc[1][0], 0, 0, 0);
        acc[1][1] = __builtin_amdgcn_mfma_f32_16x16x32_bf16(a1, b1, acc[1][1], 0, 0, 0);
    }
    // epilogue 1: out1 -> LDS O; d_out = out1 + b2
#pragma unroll
    for (int mi = 0; mi < 2; ++mi)
#pragma unroll
        for (int ni = 0; ni < 2; ++ni)
#pragma unroll
            for (int r = 0; r < 4; ++r) {
                int rl = mi * 16 + quad * 4 + r;
                int col = c0w + ni * 16 + m15;
                size_t off = (size_t)(M0 + rl) * 128 + col;
                float v = acc[mi][ni][r] + input1[off];
                O[rl][col] = v;
                outD[off] = v + b2[col];
            }
    __syncthreads();
    // epilogue 2: rmsnorm over rows of O -> h2 bf16
    {
        const int row = t >> 3, seg = t & 7;
        float4 x[4];
        float ss = 0.f;
#pragma unroll
        for (int i = 0; i < 4; ++i) {
            x[i] = *(const float4*)&O[row][seg * 16 + i * 4];
            ss += x[i].x * x[i].x + x[i].y * x[i].y + x[i].z * x[i].z + x[i].w * x[i].w;
        }
        ss += __shfl_down(ss, 4, 8);
        ss += __shfl_down(ss, 2, 8);
        ss += __shfl_down(ss, 1, 8);
        ss = __shfl(ss, 0, 8);
        float rr = rsqrtf(ss * (1.0f / 128.0f) + 1e-6f);
        ushort* hp = h2 + (size_t)(M0 + row) * 128 + seg * 16;
#pragma unroll
        for (int i = 0; i < 4; ++i) {
            float4 wv4 = *(const float4*)&ln2w[seg * 16 + i * 4];
            ushort4 o;
            o.x = f2bf(x[i].x * rr * wv4.x);
            o.y = f2bf(x[i].y * rr * wv4.y);
            o.z = f2bf(x[i].z * rr * wv4.z);
            o.w = f2bf(x[i].w * rr * wv4.w);
            *(ushort4*)&hp[i * 4] = o;
        }
    }
}

// ---------------------------------------------------------------------------
extern "C" void kernel_launch(void* const* d_in, const int* in_sizes, int n_in,
                              void* d_out, int out_size, void* d_ws, size_t ws_size,
                              hipStream_t stream) {
    const float* input1 = (const float*)d_in[0];
    const float* dis    = (const float*)d_in[1];
    const float* Wq     = (const float*)d_in[2];
    const float* Wk     = (const float*)d_in[3];
    const float* Wv     = (const float*)d_in[4];
    const float* alpha  = (const float*)d_in[5];
    const float* ln1    = (const float*)d_in[6];
    const float* ln2    = (const float*)d_in[7];
    const float* Wcomb  = (const float*)d_in[8];
    const float* W1     = (const float*)d_in[9];
    const float* b1     = (const float*)d_in[10];
    const float* W2     = (const float*)d_in[11];
    const float* b2     = (const float*)d_in[12];
    float* out = (float*)d_out;

    // workspace overlay (peak 28 MiB)
    char* w8 = (char*)d_ws;
    ushort* Wbf  = (ushort*)(w8);                  // [0, 384K)   all phases
    ushort* h_bf = (ushort*)(w8 + (1u << 20));     // [1,3M)  phase 1-2
    float*  sigq = (float*)(w8 + (4u << 20));      // [4,8M)  phase 2-4
    ushort* Mt   = (ushort*)(w8 + (8u << 20));     // [8,12M) phase 2-3
    float*  P0   = (float*)(w8 + (12u << 20));     // [12,20M) phase 3-4
    float*  P1   = (float*)(w8 + (20u << 20));     // [20,28M) phase 3-4
    ushort* h2   = (ushort*)(w8 + (1u << 20));     // [1,3M)  phase 4-5 (h_bf dead)
    ushort* mid  = (ushort*)(w8 + (12u << 20));    // [12,20M) phase 5-6 (P0 dead)

    // 1) weights->bf16 + rmsnorm1 (independent, fused dispatch)
    prep_k<<<dim3(2816), 256, 0, stream>>>(Wq, Wk, Wv, Wcomb, W1, W2, Wbf,
                                           input1, ln1, h_bf);
    // 2a) sigq = sigmoid(h @ Wq^T)
    q_sig_k<<<dim3(256), 256, 0, stream>>>(h_bf, Wbf, sigq);
    // 2b) Mt = [exp(k)*v | exp(k)]^T  (k,v GEMMs fused, transposed epilogue)
    kv_mt_k<<<dim3(256, 2), 256, 0, stream>>>(h_bf, Wbf, Mt);
    // 3) big GEMM, K-split 2
    big_gemm_k<<<dim3(128, 2, 2), 256, 0, stream>>>(dis, alpha, Mt, P0, P1);
    // 4) attn + Wcomb + residual + b2 + rmsnorm2 (out1 never materialized)
    wcomb_rms2_k<<<dim3(256), 256, 0, stream>>>(sigq, P0, P1, Wbf, input1, b2,
                                                ln2, out, h2);
    // 5) mid = relu(h2 @ W1^T + b1)
    ffn1_k<<<dim3(256, 4), 256, 0, stream>>>(h2, Wbf, b1, mid);
    // 6) out += mid @ W2^T
    ffn2_k<<<dim3(256), 256, 0, stream>>>(mid, Wbf, out);
}